// Round 3
// baseline (3372.721 us; speedup 1.0000x reference)
//
#include <hip/hip_runtime.h>
#include <hip/hip_bf16.h>

// Problem constants (static: B=4, Q0=1000, D=256, NH=8, HD=32, FF=1024, L=6, NL=4, NP=4)
#define BB 4
#define DD 256

typedef unsigned long long u64;
typedef long long s64;
typedef unsigned int u32;
typedef unsigned short u16;

__device__ __forceinline__ float bfu2f(u16 u) { union { u32 i; float f; } v; v.i = ((u32)u) << 16; return v.f; }
__device__ __forceinline__ float b2f(__hip_bfloat16 x) { return __bfloat162float(x); }

// typed load/store helpers
__device__ __forceinline__ float rd(const float* p) { return *p; }
__device__ __forceinline__ float rd(const __hip_bfloat16* p) { return b2f(*p); }
__device__ __forceinline__ float4 rd4(const float* p) { return *(const float4*)p; }
__device__ __forceinline__ float4 rd4(const __hip_bfloat16* p) {
    ushort4 v = *(const ushort4*)p;
    return make_float4(bfu2f(v.x), bfu2f(v.y), bfu2f(v.z), bfu2f(v.w));
}
__device__ __forceinline__ void wr(float* p, float v) { *p = v; }
__device__ __forceinline__ void wr(__hip_bfloat16* p, float v) { *p = __float2bfloat16(v); }

// ---------------- dtype detection ----------------
// If inputs are fp32, the EVEN u16 halves (little-endian low mantissa bits) are garbage:
// random exponent fields, some decode as |v|>=2^16 or inf/nan. If inputs are bf16, every
// u16 is a sane N(0,1) sample of query_objects. flag: 1 = bf16, 0 = f32.
__global__ void k_detect(const u16* __restrict__ q, int* __restrict__ flag) {
    __shared__ int bad;
    if (threadIdx.x == 0) bad = 0;
    __syncthreads();
    for (int i = threadIdx.x; i < 4096; i += 256) {
        u16 h = q[2 * i];
        u32 e = (h >> 7) & 0xFF;
        if (e >= 0x8F) atomicOr(&bad, 1);  // |v| >= 2^16 (or inf/nan) -> not a sane bf16 sample
    }
    __syncthreads();
    if (threadIdx.x == 0) *flag = bad ? 0 : 1;
}

// ---------------- converts / stores ----------------
template <typename T>
__global__ void k_cvt(const int* gf, int match, const void* __restrict__ in_, float* __restrict__ out, int n) {
    if (*gf != match) return;
    const T* in = (const T*)in_;
    int i = blockIdx.x * 256 + threadIdx.x;
    if (i < n) out[i] = rd(in + i);
}
template <typename T>
__global__ void k_store(const int* gf, int match, const float* __restrict__ in, void* __restrict__ out_, s64 of, int n) {
    if (*gf != match) return;
    T* out = (T*)out_ + of;
    int i = blockIdx.x * 256 + threadIdx.x;
    if (i < n) wr(out + i, in[i]);
}

// ---------------- LayerNorm (D=256, one row per block of 256 threads) ----------------
template <typename T>
__global__ void k_ln(const int* gf, int match, const float* __restrict__ x, const void* __restrict__ w_, s64 wof,
                     const void* __restrict__ b_, s64 bof, float* __restrict__ ln) {
    if (*gf != match) return;
    const T* w = (const T*)w_ + wof;
    const T* b = (const T*)b_ + bof;
    int row = blockIdx.x, tid = threadIdx.x;
    float v = x[(size_t)row * DD + tid];
    __shared__ float sred[4];
    float s = v;
#pragma unroll
    for (int o = 32; o > 0; o >>= 1) s += __shfl_down(s, o);
    if ((tid & 63) == 0) sred[tid >> 6] = s;
    __syncthreads();
    float mu = (sred[0] + sred[1] + sred[2] + sred[3]) * (1.0f / 256.0f);
    __syncthreads();
    float d = v - mu;
    float s2 = d * d;
#pragma unroll
    for (int o = 32; o > 0; o >>= 1) s2 += __shfl_down(s2, o);
    if ((tid & 63) == 0) sred[tid >> 6] = s2;
    __syncthreads();
    float var = (sred[0] + sred[1] + sred[2] + sred[3]) * (1.0f / 256.0f);
    float r = rsqrtf(var + 1e-5f);
    ln[(size_t)row * DD + tid] = d * r * rd(w + tid) + rd(b + tid);
}

// ---------------- GEMM: C[M,N] = act((A+Pe)[M,K] @ W[N,K]^T + bias) (+ residual) ----------------
template <int ACT, int RES, int PE, typename WT>
__global__ __launch_bounds__(256) void k_gemm(const int* gf, int match, const float* __restrict__ A,
                                              const float* __restrict__ Pe, const void* __restrict__ W_, s64 Wof,
                                              const void* __restrict__ B_, s64 Bof,
                                              const float* __restrict__ Rm, float* __restrict__ C,
                                              int M, int N, int K) {
    if (*gf != match) return;
    const WT* W = (const WT*)W_ + Wof;
    const WT* bias = (const WT*)B_ + Bof;
    __shared__ float As[16][64];
    __shared__ float Ws[16][64];
    int tid = threadIdx.x;
    int tx = tid & 15, ty = tid >> 4;
    int row0 = blockIdx.y * 64, col0 = blockIdx.x * 64;
    int lm = tid >> 2, lk = (tid & 3) * 4;
    float acc[4][4] = {{0.f}};
    for (int k0 = 0; k0 < K; k0 += 16) {
        int ar = row0 + lm;
        if (ar < M) {
            float4 av = *(const float4*)(A + (size_t)ar * K + k0 + lk);
            if (PE == 1) {
                float4 pv = *(const float4*)(Pe + (size_t)ar * K + k0 + lk);
                av.x += pv.x; av.y += pv.y; av.z += pv.z; av.w += pv.w;
            }
            As[lk + 0][lm] = av.x; As[lk + 1][lm] = av.y; As[lk + 2][lm] = av.z; As[lk + 3][lm] = av.w;
        } else {
            As[lk + 0][lm] = 0.f; As[lk + 1][lm] = 0.f; As[lk + 2][lm] = 0.f; As[lk + 3][lm] = 0.f;
        }
        float4 wv = rd4(W + (size_t)(col0 + lm) * K + k0 + lk);  // N multiple of 64
        Ws[lk + 0][lm] = wv.x; Ws[lk + 1][lm] = wv.y; Ws[lk + 2][lm] = wv.z; Ws[lk + 3][lm] = wv.w;
        __syncthreads();
#pragma unroll
        for (int kk = 0; kk < 16; kk++) {
            float a0 = As[kk][(ty << 2) + 0], a1 = As[kk][(ty << 2) + 1];
            float a2 = As[kk][(ty << 2) + 2], a3 = As[kk][(ty << 2) + 3];
            float w0 = Ws[kk][(tx << 2) + 0], w1 = Ws[kk][(tx << 2) + 1];
            float w2 = Ws[kk][(tx << 2) + 2], w3 = Ws[kk][(tx << 2) + 3];
            acc[0][0] += a0 * w0; acc[0][1] += a0 * w1; acc[0][2] += a0 * w2; acc[0][3] += a0 * w3;
            acc[1][0] += a1 * w0; acc[1][1] += a1 * w1; acc[1][2] += a1 * w2; acc[1][3] += a1 * w3;
            acc[2][0] += a2 * w0; acc[2][1] += a2 * w1; acc[2][2] += a2 * w2; acc[2][3] += a2 * w3;
            acc[3][0] += a3 * w0; acc[3][1] += a3 * w1; acc[3][2] += a3 * w2; acc[3][3] += a3 * w3;
        }
        __syncthreads();
    }
#pragma unroll
    for (int i2 = 0; i2 < 4; i2++) {
        int r = row0 + (ty << 2) + i2;
        if (r >= M) continue;
#pragma unroll
        for (int j2 = 0; j2 < 4; j2++) {
            int cc = col0 + (tx << 2) + j2;
            float v = acc[i2][j2] + rd(bias + cc);
            if (ACT == 1) v = fmaxf(v, 0.f);
            if (RES == 1) v += Rm[(size_t)r * N + cc];
            C[(size_t)r * N + cc] = v;
        }
    }
}

// ---------------- MHA (flash-style, HD=32, one query per thread; fp32-internal, launch once) ----------------
__global__ __launch_bounds__(64) void k_mha(const float* __restrict__ Qb, const float* __restrict__ Kb,
                                            const float* __restrict__ Vb, float* __restrict__ Ob, int Qn) {
    int bh = blockIdx.y;
    int b = bh >> 3, h = bh & 7;
    int qi = blockIdx.x * 64 + threadIdx.x;
    __shared__ float Ks[64][32];
    __shared__ float Vs[64][32];
    float qv[32];
    float acc[32];
#pragma unroll
    for (int c = 0; c < 32; c++) acc[c] = 0.f;
    float m = -INFINITY, l = 0.f;
    const float scale = 0.17677669529663687f;  // 1/sqrt(32)
    bool active = qi < Qn;
    if (active) {
        const float4* qp = (const float4*)(Qb + ((size_t)(b * Qn + qi)) * DD + h * 32);
#pragma unroll
        for (int c4 = 0; c4 < 8; c4++) {
            float4 t = qp[c4];
            qv[c4 * 4 + 0] = t.x * scale; qv[c4 * 4 + 1] = t.y * scale;
            qv[c4 * 4 + 2] = t.z * scale; qv[c4 * 4 + 3] = t.w * scale;
        }
    }
    for (int k0 = 0; k0 < Qn; k0 += 64) {
        int nk = Qn - k0; if (nk > 64) nk = 64;
        if ((int)threadIdx.x < nk) {
            const float4* kp = (const float4*)(Kb + ((size_t)(b * Qn + k0 + threadIdx.x)) * DD + h * 32);
            const float4* vp = (const float4*)(Vb + ((size_t)(b * Qn + k0 + threadIdx.x)) * DD + h * 32);
#pragma unroll
            for (int c4 = 0; c4 < 8; c4++) {
                *(float4*)&Ks[threadIdx.x][c4 * 4] = kp[c4];
                *(float4*)&Vs[threadIdx.x][c4 * 4] = vp[c4];
            }
        }
        __syncthreads();
        if (active) {
            for (int j = 0; j < nk; j++) {
                float s = 0.f;
#pragma unroll
                for (int c = 0; c < 32; c++) s += qv[c] * Ks[j][c];
                float mn = fmaxf(m, s);
                float sc = expf(m - mn);
                float p = expf(s - mn);
                l = l * sc + p;
#pragma unroll
                for (int c = 0; c < 32; c++) acc[c] = acc[c] * sc + p * Vs[j][c];
                m = mn;
            }
        }
        __syncthreads();
    }
    if (active) {
        float inv = 1.0f / l;
        float* op = Ob + ((size_t)(b * Qn + qi)) * DD + h * 32;
#pragma unroll
        for (int c = 0; c < 32; c++) op[c] = acc[c] * inv;
    }
}

// ---------------- deformable sampling ----------------
template <typename T>
__device__ __forceinline__ float d_samp(const T* fp, int W, int H, int x, int y) {
    if (x < 0 || x > W - 1 || y < 0 || y > H - 1) return 0.f;
    return rd(fp + y * W + x);
}
template <typename T>
__device__ __forceinline__ float d_bil(const T* fp, int W, int H, float gx, float gy) {
    float fx = (gx + 1.0f) * 0.5f * (float)(W - 1);
    float fy = (gy + 1.0f) * 0.5f * (float)(H - 1);
    float x0f = floorf(fx), y0f = floorf(fy);
    int x0 = (int)x0f, y0 = (int)y0f;
    float wx = fx - x0f, wy = fy - y0f;
    float v00 = d_samp(fp, W, H, x0, y0);
    float v10 = d_samp(fp, W, H, x0 + 1, y0);
    float v01 = d_samp(fp, W, H, x0, y0 + 1);
    float v11 = d_samp(fp, W, H, x0 + 1, y0 + 1);
    return v00 * (1.f - wx) * (1.f - wy) + v10 * wx * (1.f - wy) + v01 * (1.f - wx) * wy + v11 * wx * wy;
}

template <typename T>
__global__ __launch_bounds__(256) void k_deform(const int* gf, int match, const float* __restrict__ offL,
                                                const float* __restrict__ awL, const float* __restrict__ ref,
                                                const void* __restrict__ f0_, const void* __restrict__ f1_,
                                                const void* __restrict__ f2_, const void* __restrict__ f3_,
                                                float* __restrict__ caf, void* __restrict__ attn_, s64 attnOf, int Qn) {
    if (*gf != match) return;
    int row = blockIdx.x;  // b*Qn + q
    int b = row / Qn;
    int tid = threadIdx.x;
    __shared__ float attn_s[8][16];
    __shared__ float off_s[8][16][2];
    __shared__ float rxy[2];
    if (tid < 8) {
        int h = tid;
        const float* ap = awL + (size_t)row * 128 + h * 16;
        float mx = -INFINITY;
        float e[16];
#pragma unroll
        for (int j = 0; j < 16; j++) mx = fmaxf(mx, ap[j]);
        float ssum = 0.f;
#pragma unroll
        for (int j = 0; j < 16; j++) { e[j] = expf(ap[j] - mx); ssum += e[j]; }
        float inv = 1.0f / ssum;
        T* ao = (T*)attn_ + attnOf + (size_t)row * 128 + h * 16;
#pragma unroll
        for (int j = 0; j < 16; j++) {
            float p = e[j] * inv;
            attn_s[h][j] = p;
            wr(ao + j, p);
        }
        const float* op = offL + (size_t)row * 256 + h * 32;
#pragma unroll
        for (int j = 0; j < 16; j++) {
            off_s[h][j][0] = tanhf(op[j * 2 + 0]);
            off_s[h][j][1] = tanhf(op[j * 2 + 1]);
        }
    }
    if (tid == 8) {
        rxy[0] = ref[(size_t)row * 2 + 0] * 2.f - 1.f;
        rxy[1] = ref[(size_t)row * 2 + 1] * 2.f - 1.f;
    }
    __syncthreads();
    int h = tid >> 5, c = tid & 31;
    float agg = 0.f;
#pragma unroll
    for (int l = 0; l < 4; l++) {
        const int H = 128 >> l;
        const void* base = (l == 0 ? f0_ : l == 1 ? f1_ : l == 2 ? f2_ : f3_);
        const T* fp = (const T*)base + (size_t)(b * DD + h * 32 + c) * H * H;
#pragma unroll
        for (int p = 0; p < 4; p++) {
            int j = l * 4 + p;
            agg += attn_s[h][j] * d_bil(fp, H, H, rxy[0] + off_s[h][j][0], rxy[1] + off_s[h][j][1]);
        }
    }
    caf[(size_t)row * DD + h * 32 + c] = agg;
}

// ---------------- small per-row 2-output heads ----------------
template <typename T>
__global__ __launch_bounds__(64) void k_refinit(const int* gf, int match, const float* __restrict__ hbuf,
                                                const void* __restrict__ w2_, const void* __restrict__ b2_,
                                                float* __restrict__ ref) {
    if (*gf != match) return;
    const T* w2 = (const T*)w2_;
    const T* b2 = (const T*)b2_;
    int row = blockIdx.x, lane = threadIdx.x;
    const float* hp = hbuf + (size_t)row * DD;
    float s0 = 0.f, s1 = 0.f;
#pragma unroll
    for (int d = 0; d < 4; d++) {
        int dd = lane + d * 64;
        float v = hp[dd];
        s0 += v * rd(w2 + dd);
        s1 += v * rd(w2 + DD + dd);
    }
#pragma unroll
    for (int o = 32; o > 0; o >>= 1) { s0 += __shfl_down(s0, o); s1 += __shfl_down(s1, o); }
    if (lane == 0) {
        ref[(size_t)row * 2 + 0] = 1.0f / (1.0f + expf(-(s0 + rd(b2 + 0))));
        ref[(size_t)row * 2 + 1] = 1.0f / (1.0f + expf(-(s1 + rd(b2 + 1))));
    }
}

template <typename T>
__global__ __launch_bounds__(64) void k_refine(const int* gf, int match, const float* __restrict__ out,
                                               const void* __restrict__ rw_, const void* __restrict__ rb_,
                                               float* __restrict__ ref) {
    if (*gf != match) return;
    const T* rw = (const T*)rw_;
    const T* rb = (const T*)rb_;
    int row = blockIdx.x, lane = threadIdx.x;
    const float* op = out + (size_t)row * DD;
    float s0 = 0.f, s1 = 0.f;
#pragma unroll
    for (int d = 0; d < 4; d++) {
        int dd = lane + d * 64;
        float v = op[dd];
        s0 += v * rd(rw + dd);
        s1 += v * rd(rw + DD + dd);
    }
#pragma unroll
    for (int o = 32; o > 0; o >>= 1) { s0 += __shfl_down(s0, o); s1 += __shfl_down(s1, o); }
    if (lane == 0) {
        float r0 = ref[(size_t)row * 2 + 0] + tanhf(s0 + rd(rb + 0)) * 0.5f;
        float r1 = ref[(size_t)row * 2 + 1] + tanhf(s1 + rd(rb + 1)) * 0.5f;
        ref[(size_t)row * 2 + 0] = fminf(fmaxf(r0, 0.f), 1.f);
        ref[(size_t)row * 2 + 1] = fminf(fmaxf(r1, 0.f), 1.f);
    }
}

// ---------------- top-k (exact jax.lax.top_k on sigmoid scores) ----------------
template <typename T>
__global__ __launch_bounds__(256) void k_topk(const int* gf, int match, const float* __restrict__ out,
                                              const void* __restrict__ sw_, const void* __restrict__ sb_,
                                              int* __restrict__ idx, int Qn, int PAD, int keep) {
    if (*gf != match) return;
    const T* sw = (const T*)sw_;
    const T* sb = (const T*)sb_;
    __shared__ u64 keys[1024];
    int b = blockIdx.x, tid = threadIdx.x;
    for (int q = tid; q < PAD; q += 256) {
        u64 key;
        if (q < Qn) {
            float s = rd(sb + 0);
            const float* op = out + ((size_t)(b * Qn + q)) * DD;
            for (int d = 0; d < DD; d++) s += op[d] * rd(sw + d);
            float sg = 1.0f / (1.0f + expf(-s));
            u32 u = __float_as_uint(sg);
            u = (u & 0x80000000u) ? ~u : (u | 0x80000000u);
            u32 hi = ~u;  // descending score, ascending index on ties
            key = (((u64)hi) << 32) | (u32)q;
        } else {
            key = 0xFFFFFFFFFFFFFFFFULL;
        }
        keys[q] = key;
    }
    __syncthreads();
    for (int k = 2; k <= PAD; k <<= 1) {
        for (int j = k >> 1; j > 0; j >>= 1) {
            for (int i = tid; i < PAD; i += 256) {
                int ij = i ^ j;
                if (ij > i) {
                    bool up = ((i & k) == 0);
                    u64 a = keys[i], c = keys[ij];
                    if ((a > c) == up) { keys[i] = c; keys[ij] = a; }
                }
            }
            __syncthreads();
        }
    }
    for (int t = tid; t < keep; t += 256) idx[b * keep + t] = (int)(keys[t] & 0xFFFFFFFFu);
}

__global__ __launch_bounds__(256) void k_gather(const float* __restrict__ osrc, const float* __restrict__ esrc,
                                                const float* __restrict__ rsrc, const int* __restrict__ idx,
                                                float* __restrict__ oT, float* __restrict__ eT,
                                                float* __restrict__ rT, int Qin, int keep) {
    int j = blockIdx.x;
    int b = j / keep;
    int src = idx[j];
    int tid = threadIdx.x;
    size_t srow = (size_t)(b * Qin + src), drow = (size_t)j;
    oT[drow * DD + tid] = osrc[srow * DD + tid];
    eT[drow * DD + tid] = esrc[srow * DD + tid];
    if (tid < 2) rT[drow * 2 + tid] = rsrc[srow * 2 + tid];
}

__global__ __launch_bounds__(256) void k_copyback(const float* __restrict__ oT, const float* __restrict__ eT,
                                                  const float* __restrict__ rT, float* __restrict__ o,
                                                  float* __restrict__ e, float* __restrict__ r) {
    int row = blockIdx.x, tid = threadIdx.x;
    o[(size_t)row * DD + tid] = oT[(size_t)row * DD + tid];
    e[(size_t)row * DD + tid] = eT[(size_t)row * DD + tid];
    if (tid < 2) r[(size_t)row * 2 + tid] = rT[(size_t)row * 2 + tid];
}

// =======================================================================================
#define GEMM(A_, R_, P_, gx, gy, Aptr, Pe, Wb, Wof, Bb, Bof, Rm, Cp, M_, N_, K_)                                   \
    do {                                                                                                           \
        k_gemm<A_, R_, P_, float><<<dim3(gx, gy), 256, 0, stream>>>(gflag, 0, Aptr, Pe, Wb, Wof, Bb, Bof, Rm, Cp,  \
                                                                    M_, N_, K_);                                   \
        k_gemm<A_, R_, P_, __hip_bfloat16><<<dim3(gx, gy), 256, 0, stream>>>(gflag, 1, Aptr, Pe, Wb, Wof, Bb, Bof, \
                                                                             Rm, Cp, M_, N_, K_);                  \
    } while (0)

extern "C" void kernel_launch(void* const* d_in, const int* in_sizes, int n_in,
                              void* d_out, int out_size, void* d_ws, size_t ws_size,
                              hipStream_t stream) {
    (void)in_sizes; (void)n_in; (void)out_size; (void)ws_size;
    const void* q_obj = d_in[0];
    const void* q_emb = d_in[1];
    const void* feat0 = d_in[2];
    const void* feat1 = d_in[3];
    const void* feat2 = d_in[4];
    const void* feat3 = d_in[5];
    const void* sa_in_w = d_in[6];
    const void* sa_in_b = d_in[7];
    const void* sa_out_w = d_in[8];
    const void* sa_out_b = d_in[9];
    const void* off_w = d_in[10];
    const void* off_b = d_in[11];
    const void* aw_w = d_in[12];
    const void* aw_b = d_in[13];
    const void* ca_out_w = d_in[14];
    const void* ca_out_b = d_in[15];
    const void* ff_w1 = d_in[16];
    const void* ff_b1 = d_in[17];
    const void* ff_w2 = d_in[18];
    const void* ff_b2 = d_in[19];
    const void* nsa_w = d_in[20];
    const void* nsa_b = d_in[21];
    const void* nca_w = d_in[22];
    const void* nca_b = d_in[23];
    const void* nff_w = d_in[24];
    const void* nff_b = d_in[25];
    const void* ref_w1 = d_in[26];
    const void* ref_b1 = d_in[27];
    const void* ref_w2 = d_in[28];
    const void* ref_b2 = d_in[29];
    const void* score_w = d_in[30];
    const void* score_b = d_in[31];
    const void* refine_w = d_in[32];
    const void* refine_b = d_in[33];

    float* ws = (float*)d_ws;
    const int RD = 4000 * 256;  // 1,024,000 floats
    float* f_out = ws;
    float* f_emb = ws + RD;
    float* f_ln  = ws + 2 * RD;
    float* sc0   = ws + 3 * RD;
    float* sc1   = ws + 4 * RD;
    float* sc2   = ws + 5 * RD;
    float* f_ref = ws + 6 * RD;                   // 8000 floats
    int*   i_idx = (int*)(ws + 6 * RD + 8000);    // 2000 ints
    int*   gflag = (int*)(ws + 6 * RD + 10048);

    static const int Qs[6] = {1000, 500, 250, 125, 62, 31};
    static const s64 out_ofs[6] = {0, 1024000, 1536000, 1792000, 1920000, 1983488};
    static const s64 attn_ofs[6] = {2015232, 2527232, 2783232, 2911232, 2975232, 3006976};

    k_detect<<<1, 256, 0, stream>>>((const u16*)q_obj, gflag);

    // inputs -> fp32
    k_cvt<float><<<4000, 256, 0, stream>>>(gflag, 0, q_obj, f_out, RD);
    k_cvt<__hip_bfloat16><<<4000, 256, 0, stream>>>(gflag, 1, q_obj, f_out, RD);
    k_cvt<float><<<4000, 256, 0, stream>>>(gflag, 0, q_emb, f_emb, RD);
    k_cvt<__hip_bfloat16><<<4000, 256, 0, stream>>>(gflag, 1, q_emb, f_emb, RD);

    // initial reference points
    GEMM(1, 0, 0, 4, 63, f_emb, nullptr, ref_w1, 0, ref_b1, 0, nullptr, f_ln, 4000, 256, 256);
    k_refinit<float><<<4000, 64, 0, stream>>>(gflag, 0, f_ln, ref_w2, ref_b2, f_ref);
    k_refinit<__hip_bfloat16><<<4000, 64, 0, stream>>>(gflag, 1, f_ln, ref_w2, ref_b2, f_ref);

    for (int i = 0; i < 6; i++) {
        const int Q = Qs[i];
        const int R = BB * Q;
        const int gy = (R + 63) / 64;
        const s64 siwof = (s64)i * 768 * 256;
        const s64 sibof = (s64)i * 768;

        // ---- self attention ----
        k_ln<float><<<R, 256, 0, stream>>>(gflag, 0, f_out, nsa_w, i * 256, nsa_b, i * 256, f_ln);
        k_ln<__hip_bfloat16><<<R, 256, 0, stream>>>(gflag, 1, f_out, nsa_w, i * 256, nsa_b, i * 256, f_ln);
        GEMM(0, 0, 1, 4, gy, f_ln, f_emb, sa_in_w, siwof, sa_in_b, sibof, nullptr, sc0, R, 256, 256);
        GEMM(0, 0, 1, 4, gy, f_ln, f_emb, sa_in_w, siwof + 65536, sa_in_b, sibof + 256, nullptr, sc1, R, 256, 256);
        GEMM(0, 0, 0, 4, gy, f_ln, nullptr, sa_in_w, siwof + 131072, sa_in_b, sibof + 512, nullptr, sc2, R, 256, 256);
        k_mha<<<dim3((Q + 63) / 64, 32), 64, 0, stream>>>(sc0, sc1, sc2, f_ln, Q);
        GEMM(0, 1, 0, 4, gy, f_ln, nullptr, sa_out_w, (s64)i * 65536, sa_out_b, i * 256, f_out, f_out, R, 256, 256);

        // ---- deformable cross attention ----
        k_ln<float><<<R, 256, 0, stream>>>(gflag, 0, f_out, nca_w, i * 256, nca_b, i * 256, f_ln);
        k_ln<__hip_bfloat16><<<R, 256, 0, stream>>>(gflag, 1, f_out, nca_w, i * 256, nca_b, i * 256, f_ln);
        GEMM(0, 0, 1, 4, gy, f_ln, f_emb, off_w, (s64)i * 65536, off_b, i * 256, nullptr, sc0, R, 256, 256);
        GEMM(0, 0, 1, 2, gy, f_ln, f_emb, aw_w, (s64)i * 32768, aw_b, i * 128, nullptr, sc1, R, 128, 256);
        k_deform<float><<<R, 256, 0, stream>>>(gflag, 0, sc0, sc1, f_ref, feat0, feat1, feat2, feat3, sc2,
                                               d_out, attn_ofs[i], Q);
        k_deform<__hip_bfloat16><<<R, 256, 0, stream>>>(gflag, 1, sc0, sc1, f_ref, feat0, feat1, feat2, feat3, sc2,
                                                        d_out, attn_ofs[i], Q);
        GEMM(0, 1, 0, 4, gy, sc2, nullptr, ca_out_w, (s64)i * 65536, ca_out_b, i * 256, f_out, f_out, R, 256, 256);

        // ---- FFN (hidden chunked through 3*RD scratch) ----
        k_ln<float><<<R, 256, 0, stream>>>(gflag, 0, f_out, nff_w, i * 256, nff_b, i * 256, f_ln);
        k_ln<__hip_bfloat16><<<R, 256, 0, stream>>>(gflag, 1, f_out, nff_w, i * 256, nff_b, i * 256, f_ln);
        for (int r0 = 0; r0 < R; r0 += 2000) {
            int mc = R - r0; if (mc > 2000) mc = 2000;
            int gyc = (mc + 63) / 64;
            GEMM(1, 0, 0, 16, gyc, f_ln + (size_t)r0 * 256, nullptr, ff_w1, (s64)i * 262144, ff_b1, i * 1024,
                 nullptr, sc0, mc, 1024, 256);
            GEMM(0, 1, 0, 4, gyc, sc0, nullptr, ff_w2, (s64)i * 262144, ff_b2, i * 256,
                 f_out + (size_t)r0 * 256, f_out + (size_t)r0 * 256, mc, 256, 1024);
        }

        // ---- refine ref points, emit layer output ----
        if (i < 5) {
            k_refine<float><<<R, 64, 0, stream>>>(gflag, 0, f_out, refine_w, refine_b, f_ref);
            k_refine<__hip_bfloat16><<<R, 64, 0, stream>>>(gflag, 1, f_out, refine_w, refine_b, f_ref);
        }
        k_store<float><<<R, 256, 0, stream>>>(gflag, 0, f_out, d_out, out_ofs[i], R * 256);
        k_store<__hip_bfloat16><<<R, 256, 0, stream>>>(gflag, 1, f_out, d_out, out_ofs[i], R * 256);

        // ---- top-k select + gather ----
        if (i < 5) {
            int keep = Qs[i + 1];
            int PAD = 1;
            while (PAD < Q) PAD <<= 1;
            k_topk<float><<<4, 256, 0, stream>>>(gflag, 0, f_out, score_w, score_b, i_idx, Q, PAD, keep);
            k_topk<__hip_bfloat16><<<4, 256, 0, stream>>>(gflag, 1, f_out, score_w, score_b, i_idx, Q, PAD, keep);
            k_gather<<<4 * keep, 256, 0, stream>>>(f_out, f_emb, f_ref, i_idx, sc0, sc1, sc2, Q, keep);
            k_copyback<<<4 * keep, 256, 0, stream>>>(sc0, sc1, sc2, f_out, f_emb, f_ref);
        }
    }
}